// Round 1
// baseline (189.434 us; speedup 1.0000x reference)
//
#include <hip/hip_runtime.h>
#include <hip/hip_bf16.h>
#include <math.h>

// Problem constants (fixed shapes from setup_inputs):
//   B=4, N=8192, F=64; MLP: 67 -> 64 -> 32 -> 1
// d_out layout (flat, return order):
//   [0, 32768)              boundary_prob (B,N) fp32
//   [32768, 32768+2097152)  features passthrough (B,N,64) fp32
//   [2129920, 2129924)      separation_confidence (B,) fp32
#define NB 4
#define NPTS 8192
#define NF 64
#define TOTAL_PTS (NB * NPTS)
#define OUT_FEAT_OFF 32768
#define OUT_CONF_OFF (32768 + 2097152)

// ---------------------------------------------------------------------------
// Kernel A: per-point MLP + masked score + coalesced feature passthrough
// ---------------------------------------------------------------------------
__global__ __launch_bounds__(256) void mlp_kernel(
    const float* __restrict__ pts,    // (B,N,3)
    const float* __restrict__ feats,  // (B,N,64)
    const int* __restrict__ mask,     // (B,N) 0/1
    const float* __restrict__ W1,     // (64,67)
    const float* __restrict__ b1,     // (64,)
    const float* __restrict__ W2,     // (32,64)
    const float* __restrict__ b2,     // (32,)
    const float* __restrict__ W3,     // (1,32)
    const float* __restrict__ b3,     // (1,)
    float* __restrict__ out)
{
    const int t = threadIdx.x;
    const int p = blockIdx.x * 256 + t;  // 0..32767

    // ---- coalesced feature passthrough: block copies 256 points = 4096 float4
    {
        const float4* fsrc = (const float4*)feats + (size_t)blockIdx.x * 4096;
        float4* fdst = (float4*)(out + OUT_FEAT_OFF) + (size_t)blockIdx.x * 4096;
#pragma unroll
        for (int i = 0; i < 16; ++i)
            fdst[i * 256 + t] = fsrc[i * 256 + t];
    }

    // ---- layer 1: h1[j] = b1[j] + sum_k x[k] * W1[j][k],  x = [feat(64), xyz(3)]
    float h1[64];
#pragma unroll
    for (int j = 0; j < 64; ++j) h1[j] = b1[j];

    const float4* fx = (const float4*)feats + (size_t)p * 16;
    for (int kc = 0; kc < 16; ++kc) {  // dynamic, uniform loop -> scalar weight loads
        float4 xv = fx[kc];
#pragma unroll
        for (int j = 0; j < 64; ++j) {
            const float* wr = W1 + j * 67 + kc * 4;
            h1[j] = fmaf(xv.x, wr[0], h1[j]);
            h1[j] = fmaf(xv.y, wr[1], h1[j]);
            h1[j] = fmaf(xv.z, wr[2], h1[j]);
            h1[j] = fmaf(xv.w, wr[3], h1[j]);
        }
    }
    const float px = pts[(size_t)p * 3 + 0];
    const float py = pts[(size_t)p * 3 + 1];
    const float pz = pts[(size_t)p * 3 + 2];
#pragma unroll
    for (int j = 0; j < 64; ++j) {
        const float* wr = W1 + j * 67 + 64;
        h1[j] = fmaf(px, wr[0], h1[j]);
        h1[j] = fmaf(py, wr[1], h1[j]);
        h1[j] = fmaf(pz, wr[2], h1[j]);
        h1[j] = fmaxf(h1[j], 0.0f);  // relu
    }

    // ---- layer 2: h2[j] = b2[j] + sum_k h1[k] * W2[j][k]
    float h2[32];
#pragma unroll
    for (int j = 0; j < 32; ++j) h2[j] = b2[j];
#pragma unroll
    for (int k = 0; k < 64; ++k) {
        const float hv = h1[k];
#pragma unroll
        for (int j = 0; j < 32; ++j)
            h2[j] = fmaf(hv, W2[j * 64 + k], h2[j]);
    }

    // ---- layer 3 + sigmoid
    float z = b3[0];
#pragma unroll
    for (int j = 0; j < 32; ++j)
        z = fmaf(fmaxf(h2[j], 0.0f), W3[j], z);

    float s = 1.0f / (1.0f + expf(-z));
    if (mask[p] == 0) s = 0.0f;
    out[p] = s;
}

// ---------------------------------------------------------------------------
// Kernel B: per-batch stats (one block per batch, 256 threads)
// ---------------------------------------------------------------------------
__device__ __forceinline__ float blockReduceSum256(float v) {
    __shared__ float sred[4];
#pragma unroll
    for (int o = 32; o > 0; o >>= 1) v += __shfl_down(v, o, 64);
    const int w = threadIdx.x >> 6, l = threadIdx.x & 63;
    __syncthreads();  // protect sred from previous call
    if (l == 0) sred[w] = v;
    __syncthreads();
    return sred[0] + sred[1] + sred[2] + sred[3];
}

__global__ __launch_bounds__(256) void stats_kernel(
    const float* __restrict__ pts,   // (B,N,3)
    const int* __restrict__ mask,    // (B,N)
    float* __restrict__ out,         // full d_out
    float* __restrict__ ws)          // scratch: per-batch 40960 floats
{
    const int b = blockIdx.x;
    const int t = threadIdx.x;
    const int T = 256;
    const int C = NPTS / T;  // 32 contiguous indices per thread (order-preserving)

    float* scores = out + (size_t)b * NPTS;
    float* conf_out = out + OUT_CONF_OFF + b;
    const float* P = pts + (size_t)b * NPTS * 3;
    const int* M = mask + (size_t)b * NPTS;
    float* g = ws + (size_t)b * 40960;  // selected xyz, 3*8192 floats
    float* dd = g + 3 * NPTS;           // pair distances, 8192 floats

    __shared__ int cnts[256];

    // ---- pass 0: n_leaf and masked score sum
    float ss = 0.0f;
    int cm = 0;
    for (int i = t; i < NPTS; i += T) {
        const int m = (M[i] != 0);
        cm += m;
        if (m) ss += scores[i];
    }
    const float nleaf = blockReduceSum256((float)cm);
    const float ssum = blockReduceSum256(ss);

    if (nleaf < 10.0f) {
        // reference zeroes all scores and conf ends up 0
        for (int i = t; i < NPTS; i += T) scores[i] = 0.0f;
        if (t == 0) *conf_out = 0.0f;
        return;
    }

    // ---- clarity: unbiased masked variance of scores
    const float mean = ssum / fmaxf(nleaf, 1.0f);
    float vs = 0.0f;
    for (int i = t; i < NPTS; i += T) {
        if (M[i] != 0) {
            const float d0 = scores[i] - mean;
            vs += d0 * d0;
        }
    }
    const float clarity = blockReduceSum256(vs) / fmaxf(nleaf - 1.0f, 1.0f);

    // ---- order-preserving compaction of points with score > 0.7
    const int base = t * C;
    int c0 = 0;
#pragma unroll
    for (int i = 0; i < C; ++i) c0 += (scores[base + i] > 0.7f) ? 1 : 0;
    cnts[t] = c0;
    __syncthreads();
    // inclusive Hillis-Steele scan over 256 counts
    for (int off = 1; off < T; off <<= 1) {
        const int v = cnts[t];
        const int a = (t >= off) ? cnts[t - off] : 0;
        __syncthreads();
        cnts[t] = v + a;
        __syncthreads();
    }
    const int cnt = cnts[T - 1];
    int pos = cnts[t] - c0;  // exclusive prefix
    for (int i = 0; i < C; ++i) {
        const int idx = base + i;
        if (scores[idx] > 0.7f) {
            g[3 * pos + 0] = P[3 * idx + 0];
            g[3 * pos + 1] = P[3 * idx + 1];
            g[3 * pos + 2] = P[3 * idx + 2];
            ++pos;
        }
    }
    __syncthreads();

    // ---- consecutive distances among the first cnt (selected) points
    const int npair = cnt - 1;  // may be -1/0; loops no-op then
    float dsum = 0.0f;
    for (int i = t; i < npair; i += T) {
        const float ax = g[3 * i + 0] - g[3 * i + 3];
        const float ay = g[3 * i + 1] - g[3 * i + 4];
        const float az = g[3 * i + 2] - g[3 * i + 5];
        const float d0 = sqrtf(ax * ax + ay * ay + az * az);
        dd[i] = d0;
        dsum += d0;
    }
    const float dtot = blockReduceSum256(dsum);
    const float npf = (float)npair;  // sum(pair_mask) (negative -> maxed below)
    const float dmean = dtot / fmaxf(npf, 1.0f);
    float dv = 0.0f;
    for (int i = t; i < npair; i += T) {
        const float e = dd[i] - dmean;
        dv += e * e;
    }
    const float dvar = blockReduceSum256(dv) / fmaxf(npf - 1.0f, 1.0f);

    float cont = fminf(fmaxf(1.0f / (dvar + 1e-8f), 0.0f), 1.0f);
    if (!(cnt > 5)) cont = 0.0f;
    float conf = fminf(fmaxf(clarity * cont, 0.0f), 1.0f);
    // n_leaf >= 10 here, so the n_leaf==0 gate is moot
    if (t == 0) *conf_out = conf;
}

// ---------------------------------------------------------------------------
extern "C" void kernel_launch(void* const* d_in, const int* in_sizes, int n_in,
                              void* d_out, int out_size, void* d_ws, size_t ws_size,
                              hipStream_t stream) {
    const float* points   = (const float*)d_in[0];
    const float* features = (const float*)d_in[1];
    const int*   leafmask = (const int*)d_in[2];
    const float* W1 = (const float*)d_in[3];
    const float* b1 = (const float*)d_in[4];
    const float* W2 = (const float*)d_in[5];
    const float* b2 = (const float*)d_in[6];
    const float* W3 = (const float*)d_in[7];
    const float* b3 = (const float*)d_in[8];
    float* out = (float*)d_out;
    float* ws = (float*)d_ws;

    mlp_kernel<<<TOTAL_PTS / 256, 256, 0, stream>>>(
        points, features, leafmask, W1, b1, W2, b2, W3, b3, out);
    stats_kernel<<<NB, 256, 0, stream>>>(points, leafmask, out, ws);
}

// Round 2
// 108.729 us; speedup vs baseline: 1.7423x; 1.7423x over previous
//
#include <hip/hip_runtime.h>
#include <hip/hip_bf16.h>
#include <math.h>

// Shapes: B=4, N=8192, F=64; MLP: 67 -> 64 -> 32 -> 1
// d_out layout (flat): [0,32768) boundary_prob | [32768,+2097152) features | last 4: conf
#define NB 4
#define NPTS 8192
#define TOTAL_PTS (NB * NPTS)
#define OUT_FEAT_OFF 32768
#define OUT_CONF_OFF (32768 + 2097152)

// ---------------------------------------------------------------------------
// Kernel A: per-point MLP, weights staged in LDS (broadcast reads), 1 block/CU
// ---------------------------------------------------------------------------
__global__ __launch_bounds__(128) void mlp_kernel(
    const float* __restrict__ pts,    // (B,N,3)
    const float* __restrict__ feats,  // (B,N,64)
    const int* __restrict__ mask,     // (B,N)
    const float* __restrict__ W1,     // (64,67)
    const float* __restrict__ b1,
    const float* __restrict__ W2,     // (32,64)
    const float* __restrict__ b2,
    const float* __restrict__ W3,     // (1,32)
    const float* __restrict__ b3,
    float* __restrict__ out)
{
    __shared__ float sW1[67 * 64];  // transposed: sW1[k*64+j] = W1[j][k]
    __shared__ float sW2[64 * 32];  // transposed: sW2[k*32+j] = W2[j][k]
    __shared__ float sB1[64];
    __shared__ float sB2[32];
    __shared__ float sW3[32];
    __shared__ float sB3;

    const int t = threadIdx.x;
    const int p = blockIdx.x * 128 + t;

    // ---- stage weights (once per block)
    for (int idx = t; idx < 67 * 64; idx += 128) {
        const int k = idx >> 6, j = idx & 63;
        sW1[idx] = W1[j * 67 + k];
    }
    for (int idx = t; idx < 64 * 32; idx += 128) {
        const int k = idx >> 5, j = idx & 31;
        sW2[idx] = W2[j * 64 + k];
    }
    if (t < 64) sB1[t] = b1[t];
    else if (t < 96) sB2[t - 64] = b2[t - 64];
    else sW3[t - 96] = W3[t - 96];
    if (t == 0) sB3 = b3[0];

    // ---- feature passthrough while weights land: 128 pts * 16 float4
    {
        const float4* fsrc = (const float4*)feats + (size_t)blockIdx.x * 2048;
        float4* fdst = (float4*)(out + OUT_FEAT_OFF) + (size_t)blockIdx.x * 2048;
#pragma unroll
        for (int i = 0; i < 16; ++i)
            fdst[i * 128 + t] = fsrc[i * 128 + t];
    }
    __syncthreads();

    // ---- layer 1: h1[j] = b1[j] + sum_k x[k]*W1[j][k]
    float h1[64];
#pragma unroll
    for (int j = 0; j < 64; ++j) h1[j] = sB1[j];

    const float4* fx = (const float4*)feats + (size_t)p * 16;
    for (int kc = 0; kc < 16; ++kc) {  // dynamic loop: compact code
        const float4 xv = fx[kc];
        const float* r0 = &sW1[(4 * kc + 0) * 64];
        const float* r1 = &sW1[(4 * kc + 1) * 64];
        const float* r2 = &sW1[(4 * kc + 2) * 64];
        const float* r3 = &sW1[(4 * kc + 3) * 64];
#pragma unroll
        for (int j4 = 0; j4 < 16; ++j4) {
            const float4 a = *(const float4*)&r0[4 * j4];
            const float4 b = *(const float4*)&r1[4 * j4];
            const float4 c = *(const float4*)&r2[4 * j4];
            const float4 d = *(const float4*)&r3[4 * j4];
            h1[4*j4+0] = fmaf(xv.x,a.x, fmaf(xv.y,b.x, fmaf(xv.z,c.x, fmaf(xv.w,d.x, h1[4*j4+0]))));
            h1[4*j4+1] = fmaf(xv.x,a.y, fmaf(xv.y,b.y, fmaf(xv.z,c.y, fmaf(xv.w,d.y, h1[4*j4+1]))));
            h1[4*j4+2] = fmaf(xv.x,a.z, fmaf(xv.y,b.z, fmaf(xv.z,c.z, fmaf(xv.w,d.z, h1[4*j4+2]))));
            h1[4*j4+3] = fmaf(xv.x,a.w, fmaf(xv.y,b.w, fmaf(xv.z,c.w, fmaf(xv.w,d.w, h1[4*j4+3]))));
        }
    }
    // xyz tail (k = 64,65,66) + ReLU
    const float px = pts[(size_t)p * 3 + 0];
    const float py = pts[(size_t)p * 3 + 1];
    const float pz = pts[(size_t)p * 3 + 2];
    {
        const float* r0 = &sW1[64 * 64];
        const float* r1 = &sW1[65 * 64];
        const float* r2 = &sW1[66 * 64];
#pragma unroll
        for (int j4 = 0; j4 < 16; ++j4) {
            const float4 a = *(const float4*)&r0[4 * j4];
            const float4 b = *(const float4*)&r1[4 * j4];
            const float4 c = *(const float4*)&r2[4 * j4];
            h1[4*j4+0] = fmaxf(fmaf(px,a.x, fmaf(py,b.x, fmaf(pz,c.x, h1[4*j4+0]))), 0.f);
            h1[4*j4+1] = fmaxf(fmaf(px,a.y, fmaf(py,b.y, fmaf(pz,c.y, h1[4*j4+1]))), 0.f);
            h1[4*j4+2] = fmaxf(fmaf(px,a.z, fmaf(py,b.z, fmaf(pz,c.z, h1[4*j4+2]))), 0.f);
            h1[4*j4+3] = fmaxf(fmaf(px,a.w, fmaf(py,b.w, fmaf(pz,c.w, h1[4*j4+3]))), 0.f);
        }
    }

    // ---- layer 2 (fully unrolled; static h1 indices)
    float h2[32];
#pragma unroll
    for (int j = 0; j < 32; ++j) h2[j] = sB2[j];
#pragma unroll
    for (int k = 0; k < 64; ++k) {
        const float hv = h1[k];
        const float* wr = &sW2[k * 32];
#pragma unroll
        for (int j4 = 0; j4 < 8; ++j4) {
            const float4 w = *(const float4*)&wr[4 * j4];
            h2[4*j4+0] = fmaf(hv, w.x, h2[4*j4+0]);
            h2[4*j4+1] = fmaf(hv, w.y, h2[4*j4+1]);
            h2[4*j4+2] = fmaf(hv, w.z, h2[4*j4+2]);
            h2[4*j4+3] = fmaf(hv, w.w, h2[4*j4+3]);
        }
    }

    // ---- layer 3 + sigmoid + mask
    float z = sB3;
#pragma unroll
    for (int j4 = 0; j4 < 8; ++j4) {
        const float4 w = *(const float4*)&sW3[4 * j4];
        z = fmaf(fmaxf(h2[4*j4+0], 0.f), w.x, z);
        z = fmaf(fmaxf(h2[4*j4+1], 0.f), w.y, z);
        z = fmaf(fmaxf(h2[4*j4+2], 0.f), w.z, z);
        z = fmaf(fmaxf(h2[4*j4+3], 0.f), w.w, z);
    }
    float s = 1.0f / (1.0f + expf(-z));
    if (mask[p] == 0) s = 0.0f;
    out[p] = s;
}

// ---------------------------------------------------------------------------
// Kernel B helpers (1024-thread block)
// ---------------------------------------------------------------------------
__device__ __forceinline__ float bsum(float v, volatile float* sred) {
#pragma unroll
    for (int o = 32; o; o >>= 1) v += __shfl_down(v, o, 64);
    const int w = threadIdx.x >> 6, l = threadIdx.x & 63;
    __syncthreads();
    if (l == 0) sred[w] = v;
    __syncthreads();
    if (threadIdx.x < 64) {
        float x = (l < 16) ? sred[l] : 0.f;
#pragma unroll
        for (int o = 8; o; o >>= 1) x += __shfl_down(x, o, 64);
        if (l == 0) sred[16] = x;
    }
    __syncthreads();
    return sred[16];
}

__device__ __forceinline__ int bscan_excl(int c, volatile int* sw, int* total) {
    const int w = threadIdx.x >> 6, l = threadIdx.x & 63;
    int incl = c;
#pragma unroll
    for (int o = 1; o < 64; o <<= 1) {
        const int n = __shfl_up(incl, o, 64);
        if (l >= o) incl += n;
    }
    __syncthreads();
    if (l == 63) sw[w] = incl;
    __syncthreads();
    if (threadIdx.x < 64) {
        const int v = (l < 16) ? sw[l] : 0;
        int iv = v;
#pragma unroll
        for (int o = 1; o < 16; o <<= 1) {
            const int n = __shfl_up(iv, o, 64);
            if (l >= o) iv += n;
        }
        if (l < 16) sw[l] = iv - v;  // exclusive wave offset
        if (l == 15) sw[16] = iv;    // grand total
    }
    __syncthreads();
    *total = sw[16];
    return sw[w] + (incl - c);
}

// ---------------------------------------------------------------------------
// Kernel B: per-batch stats. One 1024-thread block per batch; all passes from
// registers (thread t owns contiguous indices [8t, 8t+8) — order-preserving).
// ---------------------------------------------------------------------------
__global__ __launch_bounds__(1024) void stats_kernel(
    const float* __restrict__ pts,
    const int* __restrict__ mask,
    float* __restrict__ out,
    float* __restrict__ ws)
{
    __shared__ float sred[32];
    __shared__ int sw[32];

    const int b = blockIdx.x;
    const int t = threadIdx.x;

    float* scores = out + (size_t)b * NPTS;
    const float* P = pts + (size_t)b * NPTS * 3;
    const int* M = mask + (size_t)b * NPTS;
    volatile float* g = (float*)ws + (size_t)b * 40960;  // compacted xyz
    volatile float* dd = (float*)ws + (size_t)b * 40960 + 3 * NPTS;

    // 8 contiguous scores + masks per thread, kept in registers throughout
    const float4 sa = ((const float4*)scores)[2 * t];
    const float4 sb = ((const float4*)scores)[2 * t + 1];
    const int4 ma = ((const int4*)M)[2 * t];
    const int4 mb = ((const int4*)M)[2 * t + 1];
    float s[8] = {sa.x, sa.y, sa.z, sa.w, sb.x, sb.y, sb.z, sb.w};
    int mm[8] = {ma.x, ma.y, ma.z, ma.w, mb.x, mb.y, mb.z, mb.w};

    int cm = 0;
    float ss = 0.f;
#pragma unroll
    for (int i = 0; i < 8; ++i) {
        cm += (mm[i] != 0);
        ss += s[i];  // scores already masked by kernel A
    }
    const float nleaf = bsum((float)cm, sred);
    const float ssum = bsum(ss, sred);

    if (nleaf < 10.0f) {
        const float4 z4 = {0.f, 0.f, 0.f, 0.f};
        ((float4*)scores)[2 * t] = z4;
        ((float4*)scores)[2 * t + 1] = z4;
        if (t == 0) out[OUT_CONF_OFF + b] = 0.0f;
        return;
    }

    // clarity = unbiased masked variance of scores
    const float mean = ssum / fmaxf(nleaf, 1.0f);
    float vs = 0.f;
#pragma unroll
    for (int i = 0; i < 8; ++i) {
        if (mm[i] != 0) {
            const float d0 = s[i] - mean;
            vs += d0 * d0;
        }
    }
    const float clarity = bsum(vs, sred) / fmaxf(nleaf - 1.0f, 1.0f);

    // order-preserving compaction of points with score > 0.7
    int c0 = 0;
#pragma unroll
    for (int i = 0; i < 8; ++i) c0 += (s[i] > 0.7f);
    int cnt;
    int pos = bscan_excl(c0, sw, &cnt);
#pragma unroll
    for (int i = 0; i < 8; ++i) {
        if (s[i] > 0.7f) {
            const int idx = t * 8 + i;
            g[3 * pos + 0] = P[3 * idx + 0];
            g[3 * pos + 1] = P[3 * idx + 1];
            g[3 * pos + 2] = P[3 * idx + 2];
            ++pos;
        }
    }
    __syncthreads();

    // consecutive distances among the first cnt selected points
    const int npair = cnt - 1;  // may be <=0; loops no-op
    float dsum = 0.f;
    for (int i = t; i < npair; i += 1024) {
        const float ax = g[3 * i + 0] - g[3 * i + 3];
        const float ay = g[3 * i + 1] - g[3 * i + 4];
        const float az = g[3 * i + 2] - g[3 * i + 5];
        const float d0 = sqrtf(ax * ax + ay * ay + az * az);
        dd[i] = d0;
        dsum += d0;
    }
    const float dtot = bsum(dsum, sred);
    const float npf = (float)npair;
    const float dmean = dtot / fmaxf(npf, 1.0f);
    float dv = 0.f;
    for (int i = t; i < npair; i += 1024) {
        const float e = dd[i] - dmean;
        dv += e * e;
    }
    const float dvar = bsum(dv, sred) / fmaxf(npf - 1.0f, 1.0f);

    float cont = fminf(fmaxf(1.0f / (dvar + 1e-8f), 0.0f), 1.0f);
    if (!(cnt > 5)) cont = 0.0f;
    const float conf = fminf(fmaxf(clarity * cont, 0.0f), 1.0f);
    if (t == 0) out[OUT_CONF_OFF + b] = conf;
}

// ---------------------------------------------------------------------------
extern "C" void kernel_launch(void* const* d_in, const int* in_sizes, int n_in,
                              void* d_out, int out_size, void* d_ws, size_t ws_size,
                              hipStream_t stream) {
    const float* points   = (const float*)d_in[0];
    const float* features = (const float*)d_in[1];
    const int*   leafmask = (const int*)d_in[2];
    const float* W1 = (const float*)d_in[3];
    const float* b1 = (const float*)d_in[4];
    const float* W2 = (const float*)d_in[5];
    const float* b2 = (const float*)d_in[6];
    const float* W3 = (const float*)d_in[7];
    const float* b3 = (const float*)d_in[8];
    float* out = (float*)d_out;
    float* ws = (float*)d_ws;

    mlp_kernel<<<TOTAL_PTS / 128, 128, 0, stream>>>(
        points, features, leafmask, W1, b1, W2, b2, W3, b3, out);
    stats_kernel<<<NB, 1024, 0, stream>>>(points, leafmask, out, ws);
}

// Round 4
// 107.065 us; speedup vs baseline: 1.7693x; 1.0155x over previous
//
#include <hip/hip_runtime.h>
#include <hip/hip_bf16.h>
#include <math.h>

// Shapes: B=4, N=8192, F=64; MLP: 67 -> 64 -> 32 -> 1
// d_out: [0,32768) boundary_prob | [32768,+2097152) features | last 4: conf
#define NB 4
#define NPTS 8192
#define TOTAL_PTS (NB * NPTS)
#define OUT_FEAT_OFF 32768
#define OUT_CONF_OFF (32768 + 2097152)

// ---------------------------------------------------------------------------
// block reduce over 256 threads (verified in R1)
// ---------------------------------------------------------------------------
__device__ __forceinline__ float blockReduceSum256(float v) {
    __shared__ float sred[4];
#pragma unroll
    for (int o = 32; o > 0; o >>= 1) v += __shfl_down(v, o, 64);
    const int w = threadIdx.x >> 6, l = threadIdx.x & 63;
    __syncthreads();
    if (l == 0) sred[w] = v;
    __syncthreads();
    return sred[0] + sred[1] + sred[2] + sred[3];
}

// ---------------------------------------------------------------------------
// Fused kernel: 256 blocks x 256 threads. Each block: 128 points, 2 lanes/pt.
// Last-arriving block per batch (64 blocks/batch) computes the stats.
// ---------------------------------------------------------------------------
__global__ __launch_bounds__(256) void fused_kernel(
    const float* __restrict__ pts,    // (B,N,3)
    const float* __restrict__ feats,  // (B,N,64)
    const int* __restrict__ mask,     // (B,N)
    const float* __restrict__ W1,     // (64,67)
    const float* __restrict__ b1,
    const float* __restrict__ W2,     // (32,64)
    const float* __restrict__ b2,
    const float* __restrict__ W3,     // (1,32)
    const float* __restrict__ b3,
    float* __restrict__ out,
    int* __restrict__ counters,       // 4 ints in ws, pre-zeroed
    float* __restrict__ wsf)          // stats scratch (after counters)
{
    __shared__ float sW1[67 * 64];  // sW1[k*64+j] = W1[j][k]
    __shared__ float sW2[64 * 32];  // sW2[k*32+j] = W2[j][k]
    __shared__ float sB1[64];
    __shared__ float sB2[32];
    __shared__ float sW3[32];
    __shared__ float sB3;
    __shared__ int sflag;
    __shared__ int cnts[256];

    const int t = threadIdx.x;

    // ---- stage weights (transposed) into LDS
    for (int idx = t; idx < 67 * 64; idx += 256) {
        const int k = idx >> 6, j = idx & 63;
        sW1[idx] = W1[j * 67 + k];
    }
    for (int idx = t; idx < 64 * 32; idx += 256) {
        const int k = idx >> 5, j = idx & 31;
        sW2[idx] = W2[j * 64 + k];
    }
    if (t < 64) sB1[t] = b1[t];
    else if (t < 96) sB2[t - 64] = b2[t - 64];
    else if (t < 128) sW3[t - 96] = W3[t - 96];
    if (t == 0) sB3 = b3[0];

    // ---- feature passthrough (coalesced; also warms L1/L2 for MLP reads)
    {
        const float4* fsrc = (const float4*)feats + (size_t)blockIdx.x * 2048;
        float4* fdst = (float4*)(out + OUT_FEAT_OFF) + (size_t)blockIdx.x * 2048;
#pragma unroll
        for (int i = 0; i < 8; ++i)
            fdst[i * 256 + t] = fsrc[i * 256 + t];
    }
    __syncthreads();

    // ---- MLP: wave w handles 32 points; lane l and l^32 split j-dim of a point
    const int wv = t >> 6;
    const int ln = t & 63;
    const int half = ln >> 5;
    const int pi = wv * 32 + (ln & 31);          // point within block
    const int p = blockIdx.x * 128 + pi;         // global point
    const int joff = half * 32;

    float h1[32];
#pragma unroll
    for (int j = 0; j < 32; ++j) h1[j] = sB1[joff + j];

    const float4* fx = (const float4*)feats + (size_t)p * 16;
    for (int kc = 0; kc < 16; ++kc) {
        const float4 xv = fx[kc];
        const float* r0 = &sW1[(4 * kc + 0) * 64 + joff];
        const float* r1 = &sW1[(4 * kc + 1) * 64 + joff];
        const float* r2 = &sW1[(4 * kc + 2) * 64 + joff];
        const float* r3 = &sW1[(4 * kc + 3) * 64 + joff];
#pragma unroll
        for (int j4 = 0; j4 < 8; ++j4) {
            const float4 a = *(const float4*)&r0[4 * j4];
            const float4 b = *(const float4*)&r1[4 * j4];
            const float4 c = *(const float4*)&r2[4 * j4];
            const float4 d = *(const float4*)&r3[4 * j4];
            h1[4*j4+0] = fmaf(xv.x,a.x, fmaf(xv.y,b.x, fmaf(xv.z,c.x, fmaf(xv.w,d.x, h1[4*j4+0]))));
            h1[4*j4+1] = fmaf(xv.x,a.y, fmaf(xv.y,b.y, fmaf(xv.z,c.y, fmaf(xv.w,d.y, h1[4*j4+1]))));
            h1[4*j4+2] = fmaf(xv.x,a.z, fmaf(xv.y,b.z, fmaf(xv.z,c.z, fmaf(xv.w,d.z, h1[4*j4+2]))));
            h1[4*j4+3] = fmaf(xv.x,a.w, fmaf(xv.y,b.w, fmaf(xv.z,c.w, fmaf(xv.w,d.w, h1[4*j4+3]))));
        }
    }
    // xyz tail (k=64..66) + ReLU
    const float px = pts[(size_t)p * 3 + 0];
    const float py = pts[(size_t)p * 3 + 1];
    const float pz = pts[(size_t)p * 3 + 2];
    {
        const float* r0 = &sW1[64 * 64 + joff];
        const float* r1 = &sW1[65 * 64 + joff];
        const float* r2 = &sW1[66 * 64 + joff];
#pragma unroll
        for (int j4 = 0; j4 < 8; ++j4) {
            const float4 a = *(const float4*)&r0[4 * j4];
            const float4 b = *(const float4*)&r1[4 * j4];
            const float4 c = *(const float4*)&r2[4 * j4];
            h1[4*j4+0] = fmaxf(fmaf(px,a.x, fmaf(py,b.x, fmaf(pz,c.x, h1[4*j4+0]))), 0.f);
            h1[4*j4+1] = fmaxf(fmaf(px,a.y, fmaf(py,b.y, fmaf(pz,c.y, h1[4*j4+1]))), 0.f);
            h1[4*j4+2] = fmaxf(fmaf(px,a.z, fmaf(py,b.z, fmaf(pz,c.z, h1[4*j4+2]))), 0.f);
            h1[4*j4+3] = fmaxf(fmaf(px,a.w, fmaf(py,b.w, fmaf(pz,c.w, h1[4*j4+3]))), 0.f);
        }
    }

    // ---- layer 2: this lane covers k in [joff, joff+32), all 32 outputs
    float h2[32];
#pragma unroll
    for (int j = 0; j < 32; ++j) h2[j] = half ? 0.0f : sB2[j];
#pragma unroll
    for (int k = 0; k < 32; ++k) {
        const float hv = h1[k];
        const float* wr = &sW2[(joff + k) * 32];
#pragma unroll
        for (int j4 = 0; j4 < 8; ++j4) {
            const float4 w = *(const float4*)&wr[4 * j4];
            h2[4*j4+0] = fmaf(hv, w.x, h2[4*j4+0]);
            h2[4*j4+1] = fmaf(hv, w.y, h2[4*j4+1]);
            h2[4*j4+2] = fmaf(hv, w.z, h2[4*j4+2]);
            h2[4*j4+3] = fmaf(hv, w.w, h2[4*j4+3]);
        }
    }
    // combine halves
#pragma unroll
    for (int j = 0; j < 32; ++j) h2[j] += __shfl_xor(h2[j], 32, 64);

    // ---- layer 3 + sigmoid + mask (both halves compute; half 0 stores)
    float z = sB3;
#pragma unroll
    for (int j4 = 0; j4 < 8; ++j4) {
        const float4 w = *(const float4*)&sW3[4 * j4];
        z = fmaf(fmaxf(h2[4*j4+0], 0.f), w.x, z);
        z = fmaf(fmaxf(h2[4*j4+1], 0.f), w.y, z);
        z = fmaf(fmaxf(h2[4*j4+2], 0.f), w.z, z);
        z = fmaf(fmaxf(h2[4*j4+3], 0.f), w.w, z);
    }
    float sc = 1.0f / (1.0f + expf(-z));
    if (mask[p] == 0) sc = 0.0f;
    if (half == 0) out[p] = sc;

    // ---- arrival: last block of this batch does the stats
    const int batch = blockIdx.x >> 6;
    __syncthreads();  // drains each thread's stores (vmcnt(0) before s_barrier)
    if (t == 0) {
        const int old = __hip_atomic_fetch_add(&counters[batch], 1,
                                               __ATOMIC_ACQ_REL,
                                               __HIP_MEMORY_SCOPE_AGENT);
        sflag = (old == 63);
    }
    __syncthreads();
    if (!sflag) return;
    __builtin_amdgcn_fence(__ATOMIC_ACQUIRE, "agent");  // device-scope acquire

    // ================= stats for `batch` (256 threads, 32 pts/thread) ======
    float* scores = out + (size_t)batch * NPTS;
    const float* P = pts + (size_t)batch * NPTS * 3;
    const int* M = mask + (size_t)batch * NPTS;
    float* g = wsf + (size_t)batch * 40960;   // compacted xyz
    float* dd = g + 3 * NPTS;                 // pair distances

    // load 32 contiguous scores + build mask bitfield (order-preserving)
    float s[32];
    unsigned int mbits = 0;
#pragma unroll
    for (int i = 0; i < 8; ++i) {
        const float4 s4 = ((const float4*)scores)[t * 8 + i];
        s[4*i+0] = s4.x; s[4*i+1] = s4.y; s[4*i+2] = s4.z; s[4*i+3] = s4.w;
        const int4 m4 = ((const int4*)M)[t * 8 + i];
        mbits |= (m4.x != 0 ? 1u : 0u) << (4*i+0);
        mbits |= (m4.y != 0 ? 1u : 0u) << (4*i+1);
        mbits |= (m4.z != 0 ? 1u : 0u) << (4*i+2);
        mbits |= (m4.w != 0 ? 1u : 0u) << (4*i+3);
    }

    float ss = 0.f;
#pragma unroll
    for (int i = 0; i < 32; ++i) ss += s[i];  // scores already masked
    const float nleaf = blockReduceSum256((float)__popc(mbits));
    const float ssum = blockReduceSum256(ss);

    if (nleaf < 10.0f) {
        const float4 z4 = {0.f, 0.f, 0.f, 0.f};
#pragma unroll
        for (int i = 0; i < 8; ++i) ((float4*)scores)[t * 8 + i] = z4;
        if (t == 0) out[OUT_CONF_OFF + batch] = 0.0f;
        return;
    }

    // clarity
    const float mean = ssum / fmaxf(nleaf, 1.0f);
    float vs = 0.f;
#pragma unroll
    for (int i = 0; i < 32; ++i) {
        if (mbits & (1u << i)) {
            const float d0 = s[i] - mean;
            vs += d0 * d0;
        }
    }
    const float clarity = blockReduceSum256(vs) / fmaxf(nleaf - 1.0f, 1.0f);

    // order-preserving compaction of score > 0.7 points
    int c0 = 0;
#pragma unroll
    for (int i = 0; i < 32; ++i) c0 += (s[i] > 0.7f);
    cnts[t] = c0;
    __syncthreads();
    for (int off = 1; off < 256; off <<= 1) {  // Hillis-Steele inclusive scan
        const int v = cnts[t];
        const int a = (t >= off) ? cnts[t - off] : 0;
        __syncthreads();
        cnts[t] = v + a;
        __syncthreads();
    }
    const int cnt = cnts[255];
    int pos = cnts[t] - c0;  // exclusive prefix
#pragma unroll
    for (int i = 0; i < 32; ++i) {
        if (s[i] > 0.7f) {
            const int idx = t * 32 + i;
            g[3 * pos + 0] = P[3 * idx + 0];
            g[3 * pos + 1] = P[3 * idx + 1];
            g[3 * pos + 2] = P[3 * idx + 2];
            ++pos;
        }
    }
    __syncthreads();

    // consecutive distances among first cnt selected points
    const int npair = cnt - 1;
    float dsum = 0.f;
    for (int i = t; i < npair; i += 256) {
        const float ax = g[3 * i + 0] - g[3 * i + 3];
        const float ay = g[3 * i + 1] - g[3 * i + 4];
        const float az = g[3 * i + 2] - g[3 * i + 5];
        const float d0 = sqrtf(ax * ax + ay * ay + az * az);
        dd[i] = d0;
        dsum += d0;
    }
    const float dtot = blockReduceSum256(dsum);
    const float npf = (float)npair;
    const float dmean = dtot / fmaxf(npf, 1.0f);
    float dv = 0.f;
    for (int i = t; i < npair; i += 256) {
        const float e = dd[i] - dmean;
        dv += e * e;
    }
    const float dvar = blockReduceSum256(dv) / fmaxf(npf - 1.0f, 1.0f);

    float cont = fminf(fmaxf(1.0f / (dvar + 1e-8f), 0.0f), 1.0f);
    if (!(cnt > 5)) cont = 0.0f;
    const float conf = fminf(fmaxf(clarity * cont, 0.0f), 1.0f);
    if (t == 0) out[OUT_CONF_OFF + batch] = conf;
}

// ---------------------------------------------------------------------------
extern "C" void kernel_launch(void* const* d_in, const int* in_sizes, int n_in,
                              void* d_out, int out_size, void* d_ws, size_t ws_size,
                              hipStream_t stream) {
    const float* points   = (const float*)d_in[0];
    const float* features = (const float*)d_in[1];
    const int*   leafmask = (const int*)d_in[2];
    const float* W1 = (const float*)d_in[3];
    const float* b1 = (const float*)d_in[4];
    const float* W2 = (const float*)d_in[5];
    const float* b2 = (const float*)d_in[6];
    const float* W3 = (const float*)d_in[7];
    const float* b3 = (const float*)d_in[8];
    float* out = (float*)d_out;
    int* counters = (int*)d_ws;
    float* wsf = (float*)d_ws + 64;  // stats scratch after counters

    (void)hipMemsetAsync(d_ws, 0, 64, stream);  // zero the 4 arrival counters
    fused_kernel<<<256, 256, 0, stream>>>(
        points, features, leafmask, W1, b1, W2, b2, W3, b3, out, counters, wsf);
}

// Round 5
// 106.282 us; speedup vs baseline: 1.7824x; 1.0074x over previous
//
#include <hip/hip_runtime.h>
#include <hip/hip_bf16.h>
#include <math.h>

// Shapes: B=4, N=8192, F=64; MLP: 67 -> 64 -> 32 -> 1
// d_out: [0,32768) boundary_prob | [32768,+2097152) features | last 4: conf
#define NB 4
#define NPTS 8192
#define TOTAL_PTS (NB * NPTS)
#define OUT_FEAT_OFF 32768
#define OUT_CONF_OFF (32768 + 2097152)

// ---------------------------------------------------------------------------
// block reduce over 256 threads (verified R1/R4)
// ---------------------------------------------------------------------------
__device__ __forceinline__ float blockReduceSum256(float v) {
    __shared__ float sred[4];
#pragma unroll
    for (int o = 32; o > 0; o >>= 1) v += __shfl_down(v, o, 64);
    const int w = threadIdx.x >> 6, l = threadIdx.x & 63;
    __syncthreads();
    if (l == 0) sred[w] = v;
    __syncthreads();
    return sred[0] + sred[1] + sred[2] + sred[3];
}

// ---------------------------------------------------------------------------
// Fused kernel: 512 blocks x 256 threads (2 blocks/CU -> 2 waves/SIMD).
// Each block: 64 points, 4 lanes per point (j-split by 4).
// Last-arriving block per batch (128 blocks/batch) computes the stats.
// ---------------------------------------------------------------------------
__global__ __launch_bounds__(256) void fused_kernel(
    const float* __restrict__ pts,    // (B,N,3)
    const float* __restrict__ feats,  // (B,N,64)
    const int* __restrict__ mask,     // (B,N)
    const float* __restrict__ W1,     // (64,67)
    const float* __restrict__ b1,
    const float* __restrict__ W2,     // (32,64)
    const float* __restrict__ b2,
    const float* __restrict__ W3,     // (1,32)
    const float* __restrict__ b3,
    float* __restrict__ out,
    int* __restrict__ counters,       // 4 ints in ws, pre-zeroed
    float* __restrict__ wsf)          // stats scratch (after counters)
{
    __shared__ float sW1[67 * 64];  // sW1[k*64+j] = W1[j][k]
    __shared__ float sW2[64 * 32];  // sW2[k*32+j] = W2[j][k]
    __shared__ float sB1[64];
    __shared__ float sB2[32];
    __shared__ float sW3[32];
    __shared__ float sB3;
    __shared__ int sflag;
    __shared__ int cnts[256];

    const int t = threadIdx.x;

    // ---- stage weights (transposed) into LDS
    for (int idx = t; idx < 67 * 64; idx += 256) {
        const int k = idx >> 6, j = idx & 63;
        sW1[idx] = W1[j * 67 + k];
    }
    for (int idx = t; idx < 64 * 32; idx += 256) {
        const int k = idx >> 5, j = idx & 31;
        sW2[idx] = W2[j * 64 + k];
    }
    if (t < 64) sB1[t] = b1[t];
    else if (t < 96) sB2[t - 64] = b2[t - 64];
    else if (t < 128) sW3[t - 96] = W3[t - 96];
    if (t == 0) sB3 = b3[0];

    // ---- feature passthrough (coalesced): 64 pts * 16 float4 = 1024 float4
    {
        const float4* fsrc = (const float4*)feats + (size_t)blockIdx.x * 1024;
        float4* fdst = (float4*)(out + OUT_FEAT_OFF) + (size_t)blockIdx.x * 1024;
#pragma unroll
        for (int i = 0; i < 4; ++i)
            fdst[i * 256 + t] = fsrc[i * 256 + t];
    }
    __syncthreads();

    // ---- MLP: wave handles 16 points; 4 lanes/point split the j-dimension
    const int wv = t >> 6;                 // wave in block (0..3)
    const int ln = t & 63;
    const int q = ln >> 4;                 // quarter (0..3)
    const int pi = wv * 16 + (ln & 15);    // point within block
    const int p = blockIdx.x * 64 + pi;    // global point
    const int joff = q * 16;

    float h1[16];
#pragma unroll
    for (int j = 0; j < 16; ++j) h1[j] = sB1[joff + j];

    const float4* fx = (const float4*)feats + (size_t)p * 16;
    for (int kc = 0; kc < 16; ++kc) {
        const float4 xv = fx[kc];
        const float* r0 = &sW1[(4 * kc + 0) * 64 + joff];
        const float* r1 = &sW1[(4 * kc + 1) * 64 + joff];
        const float* r2 = &sW1[(4 * kc + 2) * 64 + joff];
        const float* r3 = &sW1[(4 * kc + 3) * 64 + joff];
#pragma unroll
        for (int j4 = 0; j4 < 4; ++j4) {
            const float4 a = *(const float4*)&r0[4 * j4];
            const float4 b = *(const float4*)&r1[4 * j4];
            const float4 c = *(const float4*)&r2[4 * j4];
            const float4 d = *(const float4*)&r3[4 * j4];
            h1[4*j4+0] = fmaf(xv.x,a.x, fmaf(xv.y,b.x, fmaf(xv.z,c.x, fmaf(xv.w,d.x, h1[4*j4+0]))));
            h1[4*j4+1] = fmaf(xv.x,a.y, fmaf(xv.y,b.y, fmaf(xv.z,c.y, fmaf(xv.w,d.y, h1[4*j4+1]))));
            h1[4*j4+2] = fmaf(xv.x,a.z, fmaf(xv.y,b.z, fmaf(xv.z,c.z, fmaf(xv.w,d.z, h1[4*j4+2]))));
            h1[4*j4+3] = fmaf(xv.x,a.w, fmaf(xv.y,b.w, fmaf(xv.z,c.w, fmaf(xv.w,d.w, h1[4*j4+3]))));
        }
    }
    // xyz tail (k=64..66) + ReLU
    const float px = pts[(size_t)p * 3 + 0];
    const float py = pts[(size_t)p * 3 + 1];
    const float pz = pts[(size_t)p * 3 + 2];
    {
        const float* r0 = &sW1[64 * 64 + joff];
        const float* r1 = &sW1[65 * 64 + joff];
        const float* r2 = &sW1[66 * 64 + joff];
#pragma unroll
        for (int j4 = 0; j4 < 4; ++j4) {
            const float4 a = *(const float4*)&r0[4 * j4];
            const float4 b = *(const float4*)&r1[4 * j4];
            const float4 c = *(const float4*)&r2[4 * j4];
            h1[4*j4+0] = fmaxf(fmaf(px,a.x, fmaf(py,b.x, fmaf(pz,c.x, h1[4*j4+0]))), 0.f);
            h1[4*j4+1] = fmaxf(fmaf(px,a.y, fmaf(py,b.y, fmaf(pz,c.y, h1[4*j4+1]))), 0.f);
            h1[4*j4+2] = fmaxf(fmaf(px,a.z, fmaf(py,b.z, fmaf(pz,c.z, h1[4*j4+2]))), 0.f);
            h1[4*j4+3] = fmaxf(fmaf(px,a.w, fmaf(py,b.w, fmaf(pz,c.w, h1[4*j4+3]))), 0.f);
        }
    }

    // ---- layer 2: this lane covers k in [joff, joff+16), all 32 outputs
    float h2[32];
#pragma unroll
    for (int j = 0; j < 32; ++j) h2[j] = (q == 0) ? sB2[j] : 0.0f;
#pragma unroll
    for (int k = 0; k < 16; ++k) {
        const float hv = h1[k];
        const float* wr = &sW2[(joff + k) * 32];
#pragma unroll
        for (int j4 = 0; j4 < 8; ++j4) {
            const float4 w = *(const float4*)&wr[4 * j4];
            h2[4*j4+0] = fmaf(hv, w.x, h2[4*j4+0]);
            h2[4*j4+1] = fmaf(hv, w.y, h2[4*j4+1]);
            h2[4*j4+2] = fmaf(hv, w.z, h2[4*j4+2]);
            h2[4*j4+3] = fmaf(hv, w.w, h2[4*j4+3]);
        }
    }
    // combine the 4 quarters: q^1 (xor 16) then q^2 (xor 32)
#pragma unroll
    for (int j = 0; j < 32; ++j) h2[j] += __shfl_xor(h2[j], 16, 64);
#pragma unroll
    for (int j = 0; j < 32; ++j) h2[j] += __shfl_xor(h2[j], 32, 64);

    // ---- layer 3 + sigmoid + mask (all quarters compute; q==0 stores)
    float z = sB3;
#pragma unroll
    for (int j4 = 0; j4 < 8; ++j4) {
        const float4 w = *(const float4*)&sW3[4 * j4];
        z = fmaf(fmaxf(h2[4*j4+0], 0.f), w.x, z);
        z = fmaf(fmaxf(h2[4*j4+1], 0.f), w.y, z);
        z = fmaf(fmaxf(h2[4*j4+2], 0.f), w.z, z);
        z = fmaf(fmaxf(h2[4*j4+3], 0.f), w.w, z);
    }
    float sc = 1.0f / (1.0f + expf(-z));
    if (mask[p] == 0) sc = 0.0f;
    if (q == 0) out[p] = sc;

    // ---- arrival: last of 128 blocks of this batch does the stats
    const int batch = blockIdx.x >> 7;
    __syncthreads();  // drains stores (vmcnt(0) before s_barrier)
    if (t == 0) {
        const int old = __hip_atomic_fetch_add(&counters[batch], 1,
                                               __ATOMIC_ACQ_REL,
                                               __HIP_MEMORY_SCOPE_AGENT);
        sflag = (old == 127);
    }
    __syncthreads();
    if (!sflag) return;
    __builtin_amdgcn_fence(__ATOMIC_ACQUIRE, "agent");  // device-scope acquire

    // ================= stats for `batch` (256 threads, 32 pts/thread) ======
    float* scores = out + (size_t)batch * NPTS;
    const float* P = pts + (size_t)batch * NPTS * 3;
    const int* M = mask + (size_t)batch * NPTS;
    float* g = wsf + (size_t)batch * 40960;   // compacted xyz
    float* dd = g + 3 * NPTS;                 // pair distances

    // load 32 contiguous scores + build mask bitfield (order-preserving)
    float s[32];
    unsigned int mbits = 0;
#pragma unroll
    for (int i = 0; i < 8; ++i) {
        const float4 s4 = ((const float4*)scores)[t * 8 + i];
        s[4*i+0] = s4.x; s[4*i+1] = s4.y; s[4*i+2] = s4.z; s[4*i+3] = s4.w;
        const int4 m4 = ((const int4*)M)[t * 8 + i];
        mbits |= (m4.x != 0 ? 1u : 0u) << (4*i+0);
        mbits |= (m4.y != 0 ? 1u : 0u) << (4*i+1);
        mbits |= (m4.z != 0 ? 1u : 0u) << (4*i+2);
        mbits |= (m4.w != 0 ? 1u : 0u) << (4*i+3);
    }

    float ss = 0.f;
#pragma unroll
    for (int i = 0; i < 32; ++i) ss += s[i];  // scores already masked
    const float nleaf = blockReduceSum256((float)__popc(mbits));
    const float ssum = blockReduceSum256(ss);

    if (nleaf < 10.0f) {
        const float4 z4 = {0.f, 0.f, 0.f, 0.f};
#pragma unroll
        for (int i = 0; i < 8; ++i) ((float4*)scores)[t * 8 + i] = z4;
        if (t == 0) out[OUT_CONF_OFF + batch] = 0.0f;
        return;
    }

    // clarity
    const float mean = ssum / fmaxf(nleaf, 1.0f);
    float vs = 0.f;
#pragma unroll
    for (int i = 0; i < 32; ++i) {
        if (mbits & (1u << i)) {
            const float d0 = s[i] - mean;
            vs += d0 * d0;
        }
    }
    const float clarity = blockReduceSum256(vs) / fmaxf(nleaf - 1.0f, 1.0f);

    // order-preserving compaction of score > 0.7 points
    int c0 = 0;
#pragma unroll
    for (int i = 0; i < 32; ++i) c0 += (s[i] > 0.7f);
    cnts[t] = c0;
    __syncthreads();
    for (int off = 1; off < 256; off <<= 1) {  // Hillis-Steele inclusive scan
        const int v = cnts[t];
        const int a = (t >= off) ? cnts[t - off] : 0;
        __syncthreads();
        cnts[t] = v + a;
        __syncthreads();
    }
    const int cnt = cnts[255];
    int pos = cnts[t] - c0;  // exclusive prefix
#pragma unroll
    for (int i = 0; i < 32; ++i) {
        if (s[i] > 0.7f) {
            const int idx = t * 32 + i;
            g[3 * pos + 0] = P[3 * idx + 0];
            g[3 * pos + 1] = P[3 * idx + 1];
            g[3 * pos + 2] = P[3 * idx + 2];
            ++pos;
        }
    }
    __syncthreads();

    // consecutive distances among first cnt selected points
    const int npair = cnt - 1;
    float dsum = 0.f;
    for (int i = t; i < npair; i += 256) {
        const float ax = g[3 * i + 0] - g[3 * i + 3];
        const float ay = g[3 * i + 1] - g[3 * i + 4];
        const float az = g[3 * i + 2] - g[3 * i + 5];
        const float d0 = sqrtf(ax * ax + ay * ay + az * az);
        dd[i] = d0;
        dsum += d0;
    }
    const float dtot = blockReduceSum256(dsum);
    const float npf = (float)npair;
    const float dmean = dtot / fmaxf(npf, 1.0f);
    float dv = 0.f;
    for (int i = t; i < npair; i += 256) {
        const float e = dd[i] - dmean;
        dv += e * e;
    }
    const float dvar = blockReduceSum256(dv) / fmaxf(npf - 1.0f, 1.0f);

    float cont = fminf(fmaxf(1.0f / (dvar + 1e-8f), 0.0f), 1.0f);
    if (!(cnt > 5)) cont = 0.0f;
    const float conf = fminf(fmaxf(clarity * cont, 0.0f), 1.0f);
    if (t == 0) out[OUT_CONF_OFF + batch] = conf;
}

// ---------------------------------------------------------------------------
extern "C" void kernel_launch(void* const* d_in, const int* in_sizes, int n_in,
                              void* d_out, int out_size, void* d_ws, size_t ws_size,
                              hipStream_t stream) {
    const float* points   = (const float*)d_in[0];
    const float* features = (const float*)d_in[1];
    const int*   leafmask = (const int*)d_in[2];
    const float* W1 = (const float*)d_in[3];
    const float* b1 = (const float*)d_in[4];
    const float* W2 = (const float*)d_in[5];
    const float* b2 = (const float*)d_in[6];
    const float* W3 = (const float*)d_in[7];
    const float* b3 = (const float*)d_in[8];
    float* out = (float*)d_out;
    int* counters = (int*)d_ws;
    float* wsf = (float*)d_ws + 64;  // stats scratch after counters

    (void)hipMemsetAsync(d_ws, 0, 64, stream);  // zero the 4 arrival counters
    fused_kernel<<<512, 256, 0, stream>>>(
        points, features, leafmask, W1, b1, W2, b2, W3, b3, out, counters, wsf);
}